// Round 5
// baseline (550.564 us; speedup 1.0000x reference)
//
#include <hip/hip_runtime.h>

typedef __attribute__((ext_vector_type(8))) _Float16 half8;
typedef __attribute__((ext_vector_type(4))) _Float16 half4;
typedef __attribute__((ext_vector_type(4))) float f32x4;

#define CDIM 256
#define NDIM 4096
#define MFMAH(a, b, c) __builtin_amdgcn_mfma_f32_16x16x32_f16((a), (b), (c), 0, 0, 0)

// ---------------------------------------------------------------------------
// Cast W matrices to fp16 once per launch (L2-resident afterwards).
// ---------------------------------------------------------------------------
__global__ void cast_w_kernel(const float* __restrict__ Wq,
                              const float* __restrict__ Wk,
                              const float* __restrict__ Wv,
                              _Float16* __restrict__ Wc) {
  int t = blockIdx.x * 256 + threadIdx.x;      // 49152 float4 groups total
  int mat = t >> 14;                            // /16384
  int idx = (t & 16383) * 4;
  const float* W = (mat == 0) ? Wq : (mat == 1 ? Wk : Wv);
  float4 w = *(const float4*)(W + idx);
  half4 h = {(_Float16)w.x, (_Float16)w.y, (_Float16)w.z, (_Float16)w.w};
  *(half4*)(Wc + mat * 65536 + idx) = h;
}

// ---------------------------------------------------------------------------
// Projection: Y[b,o,n] = sum_c W[o,c] X[b,c,n] + b[o]
// Q,K -> [b][n][c]; V -> [b][c][n].
// Staging rewritten: 4-column register transpose -> ds_write_b64 (4x fewer
// LDS write instrs than scalar b16) + XOR swizzle col^((n4&7)<<3) to break
// the 4-row lane-stride bank collision (was 16-way). Swizzle mirrored on
// the fragment reads (8-half granularity preserves 16B/8B alignment).
// ---------------------------------------------------------------------------
__global__ __launch_bounds__(256, 2) void proj_kernel(
    const float* __restrict__ queries, const float* __restrict__ keys,
    const _Float16* __restrict__ Wc,
    const float* __restrict__ bq, const float* __restrict__ bk,
    const float* __restrict__ bv,
    _Float16* __restrict__ Qh, _Float16* __restrict__ Kh,
    _Float16* __restrict__ Vh)
{
  const int z = blockIdx.z, p = z >> 3, b = z & 7;
  const float* __restrict__ X = (p == 0) ? queries : keys;
  const _Float16* __restrict__ W = Wc + p * 65536;
  const float* __restrict__ bias = (p == 0) ? bq : (p == 1 ? bk : bv);
  const int n0 = blockIdx.x * 128;

  __shared__ __align__(16) _Float16 Xs[128][264];  // [n][c^swz], 528 B rows

  const int tid = threadIdx.x;
  const int wv = tid >> 6, lane = tid & 63, l16 = lane & 15, quad = lane >> 4;

  // stage X tile 128n x 256c: per iter each thread loads 4 float4 (4 c-rows,
  // same 4-n group), transposes in regs, writes 4x half4 (b64) swizzled.
#pragma unroll
  for (int it = 0; it < 8; ++it) {
    int id = tid + it * 256;
    int n4 = id & 31, c0 = (id >> 5) * 4;
    const float* Xp = &X[((size_t)(b * CDIM + c0)) * NDIM + n0 + n4 * 4];
    float4 x0 = *(const float4*)(Xp);
    float4 x1 = *(const float4*)(Xp + NDIM);
    float4 x2 = *(const float4*)(Xp + 2 * NDIM);
    float4 x3 = *(const float4*)(Xp + 3 * NDIM);
    const int cs = c0 ^ ((n4 & 7) << 3);
    half4 h;
    h = (half4){(_Float16)x0.x, (_Float16)x1.x, (_Float16)x2.x, (_Float16)x3.x};
    *(half4*)&Xs[n4 * 4 + 0][cs] = h;
    h = (half4){(_Float16)x0.y, (_Float16)x1.y, (_Float16)x2.y, (_Float16)x3.y};
    *(half4*)&Xs[n4 * 4 + 1][cs] = h;
    h = (half4){(_Float16)x0.z, (_Float16)x1.z, (_Float16)x2.z, (_Float16)x3.z};
    *(half4*)&Xs[n4 * 4 + 2][cs] = h;
    h = (half4){(_Float16)x0.w, (_Float16)x1.w, (_Float16)x2.w, (_Float16)x3.w};
    *(half4*)&Xs[n4 * 4 + 3][cs] = h;
  }
  __syncthreads();

  f32x4 acc[4][8];
#pragma unroll
  for (int og = 0; og < 4; ++og)
#pragma unroll
    for (int ng = 0; ng < 8; ++ng) acc[og][ng] = (f32x4){0.f, 0.f, 0.f, 0.f};

#pragma unroll
  for (int kc = 0; kc < 8; ++kc) {
    half8 wf[4], xf[8];
#pragma unroll
    for (int og = 0; og < 4; ++og)
      wf[og] = *(const half8*)(W + (wv * 64 + og * 16 + l16) * CDIM + kc * 32 + quad * 8);
#pragma unroll
    for (int ng = 0; ng < 8; ++ng) {
      const int row = ng * 16 + l16;
      xf[ng] = *(const half8*)&Xs[row][(kc * 32 + quad * 8) ^ (((row >> 2) & 7) << 3)];
    }
#pragma unroll
    for (int og = 0; og < 4; ++og)
#pragma unroll
      for (int ng = 0; ng < 8; ++ng)
        acc[og][ng] = MFMAH(wf[og], xf[ng], acc[og][ng]);
  }

  // epilogue: D rows = o (quad*4+r), cols = n (l16)
#pragma unroll
  for (int og = 0; og < 4; ++og) {
    float4 b4 = *(const float4*)&bias[wv * 64 + og * 16 + quad * 4];
#pragma unroll
    for (int ng = 0; ng < 8; ++ng) {
      const int n = n0 + ng * 16 + l16;
      if (p == 2) {
#pragma unroll
        for (int r = 0; r < 4; ++r) {
          int o = wv * 64 + og * 16 + quad * 4 + r;
          float y = acc[og][ng][r] + ((const float*)&b4)[r];
          Vh[((size_t)(b * CDIM + o)) * NDIM + n] = (_Float16)y;
        }
      } else {
        half4 h4;
#pragma unroll
        for (int r = 0; r < 4; ++r)
          h4[r] = (_Float16)(acc[og][ng][r] + ((const float*)&b4)[r]);
        size_t idx = ((size_t)(b * NDIM + n)) * CDIM + wv * 64 + og * 16 + quad * 4;
        if (p == 0) *(half4*)&Qh[idx] = h4;
        else        *(half4*)&Kh[idx] = h4;
      }
    }
  }
}

// ---------------------------------------------------------------------------
// Flash attention: round-0 proven structure (16x16 MFMA, Al/Li rescale),
// with ONE change: K tile register-prefetch (T14). Tile jt+1's global loads
// are issued right after tile jt's regs are written to LDS, giving a full
// iteration (~QK+softmax+PV) to cover L2/HBM latency instead of exposing it
// between loop-top and B1. Race-free: after B2(jt-1) no wave reads Ks until
// B1(jt), so the loop-top ds_writes are safe (same argument as before).
// ---------------------------------------------------------------------------
__global__ __launch_bounds__(256, 2) void attn_kernel(
    const float* __restrict__ queries, const float* __restrict__ mask,
    const _Float16* __restrict__ Qh, const _Float16* __restrict__ Kh,
    const _Float16* __restrict__ Vh, float* __restrict__ out)
{
  const int blk = blockIdx.x, b = blk & 7, it = blk >> 3;  // b=blk&7: XCD L2
  const int i0 = it * 64;

  __shared__ __align__(16) _Float16 Ks[64][264];    // [j][c]  33792 B
  __shared__ __align__(16) _Float16 Ps[2][64][72];  // [i][j]  18432 B (dbuf)
  __shared__ __align__(16) float Al[2][64];         // alpha per i-row (dbuf)
  __shared__ __align__(16) float Li[64];            // 1/l per i-row

  const int tid = threadIdx.x;
  const int wv = tid >> 6, lane = tid & 63, l16 = lane & 15, quad = lane >> 4;

  // Q fragments: B-operand layout (n=l16 -> i-row, k=quad*8+t -> c)
  half8 qf[8];
  {
    const size_t qrow = ((size_t)(b * NDIM + i0 + wv * 16 + l16)) * CDIM;
#pragma unroll
    for (int kc = 0; kc < 8; ++kc)
      qf[kc] = *(const half8*)(Qh + qrow + kc * 32 + quad * 8);
  }
  // per-lane softmax state: this lane's i-row is i0 + wv*16 + l16
  const float mval = mask[(size_t)b * NDIM + i0 + wv * 16 + l16];
  float m_run = -1e30f, l_run = 0.f;

  f32x4 O[4][4];  // [i-group][ch-group], wave's ch base = wv*64
#pragma unroll
  for (int g = 0; g < 4; ++g)
#pragma unroll
    for (int cg = 0; cg < 4; ++cg) O[g][cg] = (f32x4){0.f, 0.f, 0.f, 0.f};

  const _Float16* __restrict__ Kb = Kh + (size_t)b * NDIM * CDIM;
  const _Float16* __restrict__ Vw = Vh + ((size_t)(b * CDIM + wv * 64)) * NDIM;

  // prologue: prefetch K tile 0 into registers
  uint4 kreg[8];
#pragma unroll
  for (int st = 0; st < 8; ++st) {
    int id = tid + st * 256;
    int j = id >> 5, c8 = id & 31;
    kreg[st] = *(const uint4*)(Kb + (size_t)j * CDIM + c8 * 8);
  }

  for (int jt = 0; jt < 64; ++jt) {
    const int j0 = jt * 64;
    const int pb = jt & 1;
    // write prefetched K tile to LDS (safe: no Ks reads between B2(jt-1) and B1)
#pragma unroll
    for (int st = 0; st < 8; ++st) {
      int id = tid + st * 256;
      int j = id >> 5, c8 = id & 31;
      *(uint4*)&Ks[j][c8 * 8] = kreg[st];
    }
    // issue NEXT tile's K loads now: a full iteration to cover latency
    // (last iter wraps to tile 0 — valid memory, avoids a branch)
    const int jn = ((jt + 1) & 63) * 64;
#pragma unroll
    for (int st = 0; st < 8; ++st) {
      int id = tid + st * 256;
      int j = id >> 5, c8 = id & 31;
      kreg[st] = *(const uint4*)(Kb + (size_t)(jn + j) * CDIM + c8 * 8);
    }
    // V fragments for this tile direct from global (held across QK/softmax;
    // vmcnt waited only at first PV use -> overlaps with QK compute)
    half8 vf[2][4];
#pragma unroll
    for (int kk = 0; kk < 2; ++kk)
#pragma unroll
      for (int cg = 0; cg < 4; ++cg)
        vf[kk][cg] = *(const half8*)(Vw + (size_t)(cg * 16 + l16) * NDIM + j0 + kk * 32 + quad * 8);
    __syncthreads();  // B1: Ks staged

    // S^T = K Q^T: D[m=j][n=i]; lane holds 16 j-values for i = wv*16+l16
    f32x4 s[4];
#pragma unroll
    for (int js = 0; js < 4; ++js) s[js] = (f32x4){0.f, 0.f, 0.f, 0.f};
#pragma unroll
    for (int kc = 0; kc < 8; ++kc) {
#pragma unroll
      for (int js = 0; js < 4; ++js) {
        half8 kf = *(const half8*)&Ks[js * 16 + l16][kc * 32 + quad * 8];
        s[js] = MFMAH(kf, qf[kc], s[js]);
      }
    }

    // online softmax, in-lane over 16 j-values + cross-quad (xor16, xor32)
    float a[16];
    float mx = -1e30f;
#pragma unroll
    for (int js = 0; js < 4; ++js)
#pragma unroll
      for (int r = 0; r < 4; ++r) {
        float v = s[js][r] * mval;
        a[js * 4 + r] = v;
        mx = fmaxf(mx, v);
      }
    mx = fmaxf(mx, __shfl_xor(mx, 16));
    mx = fmaxf(mx, __shfl_xor(mx, 32));
    const float mnew = fmaxf(m_run, mx);
    const float alpha = __expf(m_run - mnew);
    m_run = mnew;
    float psum = 0.f;
#pragma unroll
    for (int js = 0; js < 4; ++js) {
      float p0 = __expf(a[js * 4 + 0] - mnew);
      float p1 = __expf(a[js * 4 + 1] - mnew);
      float p2 = __expf(a[js * 4 + 2] - mnew);
      float p3 = __expf(a[js * 4 + 3] - mnew);
      psum += (p0 + p1) + (p2 + p3);
      half4 hp = {(_Float16)p0, (_Float16)p1, (_Float16)p2, (_Float16)p3};
      // P[i][j]: i = wv*16+l16, j = js*16 + quad*4 + r
      *(half4*)&Ps[pb][wv * 16 + l16][js * 16 + quad * 4] = hp;
    }
    psum += __shfl_xor(psum, 16);
    psum += __shfl_xor(psum, 32);
    l_run = l_run * alpha + psum;
    if (quad == 0) Al[pb][wv * 16 + l16] = alpha;
    __syncthreads();  // B2: Ps/Al visible

    // O rescale + O += P V  (wave covers all 64 i, channels [wv*64, +64))
    f32x4 av[4];
#pragma unroll
    for (int g = 0; g < 4; ++g) av[g] = *(const f32x4*)&Al[pb][g * 16 + quad * 4];
#pragma unroll
    for (int g = 0; g < 4; ++g)
#pragma unroll
      for (int cg = 0; cg < 4; ++cg)
#pragma unroll
        for (int r = 0; r < 4; ++r) O[g][cg][r] *= av[g][r];
#pragma unroll
    for (int kk = 0; kk < 2; ++kk) {
      half8 pa[4];
#pragma unroll
      for (int g = 0; g < 4; ++g)
        pa[g] = *(const half8*)&Ps[pb][g * 16 + l16][kk * 32 + quad * 8];
#pragma unroll
      for (int g = 0; g < 4; ++g)
#pragma unroll
        for (int cg = 0; cg < 4; ++cg)
          O[g][cg] = MFMAH(pa[g], vf[kk][cg], O[g][cg]);
    }
  }

  // publish 1/l, then blended epilogue
  if (quad == 0) Li[wv * 16 + l16] = 1.0f / l_run;
  __syncthreads();
#pragma unroll
  for (int g = 0; g < 4; ++g) {
    f32x4 li4 = *(const f32x4*)&Li[g * 16 + quad * 4];
    const int i = i0 + g * 16 + quad * 4;
    float4 m4 = *(const float4*)&mask[(size_t)b * NDIM + i];
#pragma unroll
    for (int cg = 0; cg < 4; ++cg) {
      const int c = wv * 64 + cg * 16 + l16;
      const size_t base = ((size_t)(b * CDIM + c)) * NDIM + i;
      float4 q4 = *(const float4*)(queries + base);
      float4 o4;
      o4.x = q4.x * m4.x + (1.f - m4.x) * (O[g][cg][0] * li4[0]);
      o4.y = q4.y * m4.y + (1.f - m4.y) * (O[g][cg][1] * li4[1]);
      o4.z = q4.z * m4.z + (1.f - m4.z) * (O[g][cg][2] * li4[2]);
      o4.w = q4.w * m4.w + (1.f - m4.w) * (O[g][cg][3] * li4[3]);
      *(float4*)(out + base) = o4;
    }
  }
}

extern "C" void kernel_launch(void* const* d_in, const int* in_sizes, int n_in,
                              void* d_out, int out_size, void* d_ws, size_t ws_size,
                              hipStream_t stream) {
  const float* queries = (const float*)d_in[0];
  const float* keys    = (const float*)d_in[1];
  const float* mask    = (const float*)d_in[2];
  const float* Wq = (const float*)d_in[3];
  const float* bq = (const float*)d_in[4];
  const float* Wk = (const float*)d_in[5];
  const float* bk = (const float*)d_in[6];
  const float* Wv = (const float*)d_in[7];
  const float* bv = (const float*)d_in[8];
  float* out = (float*)d_out;

  const size_t elems = (size_t)8 * NDIM * CDIM;
  _Float16* Qh = (_Float16*)d_ws;
  _Float16* Kh = Qh + elems;
  _Float16* Vh = Kh + elems;
  _Float16* Wc = Vh + elems;   // 3*65536 fp16

  cast_w_kernel<<<dim3(192), 256, 0, stream>>>(Wq, Wk, Wv, Wc);
  proj_kernel<<<dim3(32, 1, 24), 256, 0, stream>>>(
      queries, keys, Wc, bq, bk, bv, Qh, Kh, Vh);
  attn_kernel<<<dim3(512), 256, 0, stream>>>(
      queries, mask, Qh, Kh, Vh, out);
}

// Round 6
// 335.604 us; speedup vs baseline: 1.6405x; 1.6405x over previous
//
#include <hip/hip_runtime.h>

typedef __attribute__((ext_vector_type(8))) _Float16 half8;
typedef __attribute__((ext_vector_type(4))) _Float16 half4;
typedef __attribute__((ext_vector_type(4))) float f32x4;

#define CDIM 256
#define NDIM 4096
#define MFMAH(a, b, c) __builtin_amdgcn_mfma_f32_16x16x32_f16((a), (b), (c), 0, 0, 0)

// async global->LDS DMA, 16B per lane (spill-proof staging path)
#define GLOAD_LDS16(gp, lp)                                              \
  __builtin_amdgcn_global_load_lds(                                      \
      (const __attribute__((address_space(1))) void*)(gp),               \
      (__attribute__((address_space(3))) void*)(lp), 16, 0, 0)

// ---------------------------------------------------------------------------
// Cast W matrices to fp16 once per launch (L2-resident afterwards).
// ---------------------------------------------------------------------------
__global__ void cast_w_kernel(const float* __restrict__ Wq,
                              const float* __restrict__ Wk,
                              const float* __restrict__ Wv,
                              _Float16* __restrict__ Wc) {
  int t = blockIdx.x * 256 + threadIdx.x;      // 49152 float4 groups total
  int mat = t >> 14;                            // /16384
  int idx = (t & 16383) * 4;
  const float* W = (mat == 0) ? Wq : (mat == 1 ? Wk : Wv);
  float4 w = *(const float4*)(W + idx);
  half4 h = {(_Float16)w.x, (_Float16)w.y, (_Float16)w.z, (_Float16)w.w};
  *(half4*)(Wc + mat * 65536 + idx) = h;
}

// ---------------------------------------------------------------------------
// Projection (round-5 version, perf-neutral vs round-0): Y = W X + b
// Q,K -> [b][n][c]; V -> [b][c][n].
// ---------------------------------------------------------------------------
__global__ __launch_bounds__(256, 2) void proj_kernel(
    const float* __restrict__ queries, const float* __restrict__ keys,
    const _Float16* __restrict__ Wc,
    const float* __restrict__ bq, const float* __restrict__ bk,
    const float* __restrict__ bv,
    _Float16* __restrict__ Qh, _Float16* __restrict__ Kh,
    _Float16* __restrict__ Vh)
{
  const int z = blockIdx.z, p = z >> 3, b = z & 7;
  const float* __restrict__ X = (p == 0) ? queries : keys;
  const _Float16* __restrict__ W = Wc + p * 65536;
  const float* __restrict__ bias = (p == 0) ? bq : (p == 1 ? bk : bv);
  const int n0 = blockIdx.x * 128;

  __shared__ __align__(16) _Float16 Xs[128][264];  // [n][c^swz], 528 B rows

  const int tid = threadIdx.x;
  const int wv = tid >> 6, lane = tid & 63, l16 = lane & 15, quad = lane >> 4;

#pragma unroll
  for (int it = 0; it < 8; ++it) {
    int id = tid + it * 256;
    int n4 = id & 31, c0 = (id >> 5) * 4;
    const float* Xp = &X[((size_t)(b * CDIM + c0)) * NDIM + n0 + n4 * 4];
    float4 x0 = *(const float4*)(Xp);
    float4 x1 = *(const float4*)(Xp + NDIM);
    float4 x2 = *(const float4*)(Xp + 2 * NDIM);
    float4 x3 = *(const float4*)(Xp + 3 * NDIM);
    const int cs = c0 ^ ((n4 & 7) << 3);
    half4 h;
    h = (half4){(_Float16)x0.x, (_Float16)x1.x, (_Float16)x2.x, (_Float16)x3.x};
    *(half4*)&Xs[n4 * 4 + 0][cs] = h;
    h = (half4){(_Float16)x0.y, (_Float16)x1.y, (_Float16)x2.y, (_Float16)x3.y};
    *(half4*)&Xs[n4 * 4 + 1][cs] = h;
    h = (half4){(_Float16)x0.z, (_Float16)x1.z, (_Float16)x2.z, (_Float16)x3.z};
    *(half4*)&Xs[n4 * 4 + 2][cs] = h;
    h = (half4){(_Float16)x0.w, (_Float16)x1.w, (_Float16)x2.w, (_Float16)x3.w};
    *(half4*)&Xs[n4 * 4 + 3][cs] = h;
  }
  __syncthreads();

  f32x4 acc[4][8];
#pragma unroll
  for (int og = 0; og < 4; ++og)
#pragma unroll
    for (int ng = 0; ng < 8; ++ng) acc[og][ng] = (f32x4){0.f, 0.f, 0.f, 0.f};

#pragma unroll
  for (int kc = 0; kc < 8; ++kc) {
    half8 wf[4], xf[8];
#pragma unroll
    for (int og = 0; og < 4; ++og)
      wf[og] = *(const half8*)(W + (wv * 64 + og * 16 + l16) * CDIM + kc * 32 + quad * 8);
#pragma unroll
    for (int ng = 0; ng < 8; ++ng) {
      const int row = ng * 16 + l16;
      xf[ng] = *(const half8*)&Xs[row][(kc * 32 + quad * 8) ^ (((row >> 2) & 7) << 3)];
    }
#pragma unroll
    for (int og = 0; og < 4; ++og)
#pragma unroll
      for (int ng = 0; ng < 8; ++ng)
        acc[og][ng] = MFMAH(wf[og], xf[ng], acc[og][ng]);
  }

#pragma unroll
  for (int og = 0; og < 4; ++og) {
    float4 b4 = *(const float4*)&bias[wv * 64 + og * 16 + quad * 4];
#pragma unroll
    for (int ng = 0; ng < 8; ++ng) {
      const int n = n0 + ng * 16 + l16;
      if (p == 2) {
#pragma unroll
        for (int r = 0; r < 4; ++r) {
          int o = wv * 64 + og * 16 + quad * 4 + r;
          float y = acc[og][ng][r] + ((const float*)&b4)[r];
          Vh[((size_t)(b * CDIM + o)) * NDIM + n] = (_Float16)y;
        }
      } else {
        half4 h4;
#pragma unroll
        for (int r = 0; r < 4; ++r)
          h4[r] = (_Float16)(acc[og][ng][r] + ((const float*)&b4)[r]);
        size_t idx = ((size_t)(b * NDIM + n)) * CDIM + wv * 64 + og * 16 + quad * 4;
        if (p == 0) *(half4*)&Qh[idx] = h4;
        else        *(half4*)&Kh[idx] = h4;
      }
    }
  }
}

// ---------------------------------------------------------------------------
// Flash attention: round-0 proven structure (16x16 MFMA, Al/Li rescale),
// with surgical changes only:
//  1. K staging via global_load_lds DMA (no VGPR round-trip -> cannot spill;
//     no staging VALU; LDS writes on TA path -> no SQ bank conflicts).
//     Ks is LINEAR [64][256]; conflict-freedom on kf reads comes from a
//     content swizzle col^((row&7)<<3) applied on the per-lane GLOBAL source
//     address (XOR lives in byte bits 4-6 => within one 128B line => global
//     coalescing untouched) and mirrored on the ds_read address.
//  2. Pipelined issue: tile jt+1's DMA issued right AFTER B2(jt) (all Ks
//     reads of jt complete before B2), so the whole PV phase + loop-top
//     covers the L2 latency; B1(jt+1)'s barrier drain completes it.
//  3. exp2-domain softmax (mask premultiplied by log2e): 16 fewer VALU/jt.
// ---------------------------------------------------------------------------
__global__ __launch_bounds__(256, 2) void attn_kernel(
    const float* __restrict__ queries, const float* __restrict__ mask,
    const _Float16* __restrict__ Qh, const _Float16* __restrict__ Kh,
    const _Float16* __restrict__ Vh, float* __restrict__ out)
{
  const int blk = blockIdx.x, b = blk & 7, it = blk >> 3;  // b=blk&7: XCD L2
  const int i0 = it * 64;

  __shared__ __align__(16) _Float16 Ks[64 * 256];   // linear, swizzled content
  __shared__ __align__(16) _Float16 Ps[2][64][72];  // [i][j]  18432 B (dbuf)
  __shared__ __align__(16) float Al[2][64];         // alpha per i-row (dbuf)
  __shared__ __align__(16) float Li[64];            // 1/l per i-row

  const int tid = threadIdx.x;
  const int wv = tid >> 6, lane = tid & 63, l16 = lane & 15, quad = lane >> 4;

  const float LOG2E = 1.44269504088896f;

  // Q fragments: B-operand layout (n=l16 -> i-row, k=quad*8+t -> c)
  half8 qf[8];
  {
    const size_t qrow = ((size_t)(b * NDIM + i0 + wv * 16 + l16)) * CDIM;
#pragma unroll
    for (int kc = 0; kc < 8; ++kc)
      qf[kc] = *(const half8*)(Qh + qrow + kc * 32 + quad * 8);
  }
  // per-lane softmax state: this lane's i-row is i0 + wv*16 + l16
  const float mvalL = mask[(size_t)b * NDIM + i0 + wv * 16 + l16] * LOG2E;
  float m_run = -1e30f, l_run = 0.f;

  f32x4 O[4][4];  // [i-group][ch-group], wave's ch base = wv*64
#pragma unroll
  for (int g = 0; g < 4; ++g)
#pragma unroll
    for (int cg = 0; cg < 4; ++cg) O[g][cg] = (f32x4){0.f, 0.f, 0.f, 0.f};

  const _Float16* __restrict__ Kb = Kh + (size_t)b * NDIM * CDIM;
  const _Float16* __restrict__ Vw = Vh + ((size_t)(b * CDIM + wv * 64)) * NDIM;

  // staging geometry (loop-invariant): thread handles chunk row jrow (0..7),
  // 16B block (tid&31) of each 512B K row; source col pre-swizzled.
  const int jrow = tid >> 5;                                   // 0..7
  const int scol = ((tid & 31) * 8) ^ ((jrow & 7) << 3);       // halfs
  char* const ldst0 = (char*)Ks + (size_t)tid * 16;            // +st*4096
  const int kswz = (l16 & 7) << 3;                             // read-side XOR

  // prologue: issue DMA for K tile 0
#pragma unroll
  for (int st = 0; st < 8; ++st)
    GLOAD_LDS16(Kb + (size_t)(st * 8 + jrow) * CDIM + scol, ldst0 + st * 4096);

  for (int jt = 0; jt < 64; ++jt) {
    const int j0 = jt * 64;
    const int pb = jt & 1;
    // V fragments for this tile direct from global (held across QK/softmax)
    half8 vf[2][4];
#pragma unroll
    for (int kk = 0; kk < 2; ++kk)
#pragma unroll
      for (int cg = 0; cg < 4; ++cg)
        vf[kk][cg] = *(const half8*)(Vw + (size_t)(cg * 16 + l16) * NDIM + j0 + kk * 32 + quad * 8);
    __syncthreads();  // B1: barrier drain (vmcnt 0) completes K DMA

    // S^T = K Q^T: D[m=j][n=i]; lane holds 16 j-values for i = wv*16+l16
    f32x4 s[4];
#pragma unroll
    for (int js = 0; js < 4; ++js) s[js] = (f32x4){0.f, 0.f, 0.f, 0.f};
#pragma unroll
    for (int kc = 0; kc < 8; ++kc) {
#pragma unroll
      for (int js = 0; js < 4; ++js) {
        half8 kf = *(const half8*)&Ks[(js * 16 + l16) * 256 + ((kc * 32 + quad * 8) ^ kswz)];
        s[js] = MFMAH(kf, qf[kc], s[js]);
      }
    }

    // online softmax (exp2 domain), in-lane over 16 j + cross-quad reduce
    float a[16];
    float mx = -1e30f;
#pragma unroll
    for (int js = 0; js < 4; ++js)
#pragma unroll
      for (int r = 0; r < 4; ++r) {
        float v = s[js][r] * mvalL;
        a[js * 4 + r] = v;
        mx = fmaxf(mx, v);
      }
    mx = fmaxf(mx, __shfl_xor(mx, 16));
    mx = fmaxf(mx, __shfl_xor(mx, 32));
    const float mnew = fmaxf(m_run, mx);
    const float alpha = exp2f(m_run - mnew);
    m_run = mnew;
    float psum = 0.f;
#pragma unroll
    for (int js = 0; js < 4; ++js) {
      float p0 = exp2f(a[js * 4 + 0] - mnew);
      float p1 = exp2f(a[js * 4 + 1] - mnew);
      float p2 = exp2f(a[js * 4 + 2] - mnew);
      float p3 = exp2f(a[js * 4 + 3] - mnew);
      psum += (p0 + p1) + (p2 + p3);
      half4 hp = {(_Float16)p0, (_Float16)p1, (_Float16)p2, (_Float16)p3};
      // P[i][j]: i = wv*16+l16, j = js*16 + quad*4 + r
      *(half4*)&Ps[pb][wv * 16 + l16][js * 16 + quad * 4] = hp;
    }
    psum += __shfl_xor(psum, 16);
    psum += __shfl_xor(psum, 32);
    l_run = l_run * alpha + psum;
    if (quad == 0) Al[pb][wv * 16 + l16] = alpha;
    __syncthreads();  // B2: Ps/Al visible; all Ks reads of jt complete

    // issue NEXT K tile's DMA now -> latency hidden under PV + next loop-top
    if (jt < 63) {
      const _Float16* srcn = Kb + (size_t)((jt + 1) * 64 + jrow) * CDIM + scol;
#pragma unroll
      for (int st = 0; st < 8; ++st)
        GLOAD_LDS16(srcn + (size_t)st * 8 * CDIM, ldst0 + st * 4096);
    }

    // O rescale + O += P V  (wave covers all 64 i, channels [wv*64, +64))
    f32x4 av[4];
#pragma unroll
    for (int g = 0; g < 4; ++g) av[g] = *(const f32x4*)&Al[pb][g * 16 + quad * 4];
#pragma unroll
    for (int g = 0; g < 4; ++g)
#pragma unroll
      for (int cg = 0; cg < 4; ++cg)
#pragma unroll
        for (int r = 0; r < 4; ++r) O[g][cg][r] *= av[g][r];
#pragma unroll
    for (int kk = 0; kk < 2; ++kk) {
      half8 pa[4];
#pragma unroll
      for (int g = 0; g < 4; ++g)
        pa[g] = *(const half8*)&Ps[pb][g * 16 + l16][kk * 32 + quad * 8];
#pragma unroll
      for (int g = 0; g < 4; ++g)
#pragma unroll
        for (int cg = 0; cg < 4; ++cg)
          O[g][cg] = MFMAH(pa[g], vf[kk][cg], O[g][cg]);
    }
  }

  // publish 1/l, then blended epilogue
  if (quad == 0) Li[wv * 16 + l16] = 1.0f / l_run;
  __syncthreads();
#pragma unroll
  for (int g = 0; g < 4; ++g) {
    f32x4 li4 = *(const f32x4*)&Li[g * 16 + quad * 4];
    const int i = i0 + g * 16 + quad * 4;
    float4 m4 = *(const float4*)&mask[(size_t)b * NDIM + i];
#pragma unroll
    for (int cg = 0; cg < 4; ++cg) {
      const int c = wv * 64 + cg * 16 + l16;
      const size_t base = ((size_t)(b * CDIM + c)) * NDIM + i;
      float4 q4 = *(const float4*)(queries + base);
      float4 o4;
      o4.x = q4.x * m4.x + (1.f - m4.x) * (O[g][cg][0] * li4[0]);
      o4.y = q4.y * m4.y + (1.f - m4.y) * (O[g][cg][1] * li4[1]);
      o4.z = q4.z * m4.z + (1.f - m4.z) * (O[g][cg][2] * li4[2]);
      o4.w = q4.w * m4.w + (1.f - m4.w) * (O[g][cg][3] * li4[3]);
      *(float4*)(out + base) = o4;
    }
  }
}

extern "C" void kernel_launch(void* const* d_in, const int* in_sizes, int n_in,
                              void* d_out, int out_size, void* d_ws, size_t ws_size,
                              hipStream_t stream) {
  const float* queries = (const float*)d_in[0];
  const float* keys    = (const float*)d_in[1];
  const float* mask    = (const float*)d_in[2];
  const float* Wq = (const float*)d_in[3];
  const float* bq = (const float*)d_in[4];
  const float* Wk = (const float*)d_in[5];
  const float* bk = (const float*)d_in[6];
  const float* Wv = (const float*)d_in[7];
  const float* bv = (const float*)d_in[8];
  float* out = (float*)d_out;

  const size_t elems = (size_t)8 * NDIM * CDIM;
  _Float16* Qh = (_Float16*)d_ws;
  _Float16* Kh = Qh + elems;
  _Float16* Vh = Kh + elems;
  _Float16* Wc = Vh + elems;   // 3*65536 fp16

  cast_w_kernel<<<dim3(192), 256, 0, stream>>>(Wq, Wk, Wv, Wc);
  proj_kernel<<<dim3(32, 1, 24), 256, 0, stream>>>(
      queries, keys, Wc, bq, bk, bv, Qh, Kh, Vh);
  attn_kernel<<<dim3(512), 256, 0, stream>>>(
      queries, mask, Qh, Kh, Vh, out);
}